// Round 1
// baseline (1926.180 us; speedup 1.0000x reference)
//
#include <hip/hip_runtime.h>
#include <cstdint>
#include <cstddef>

#define DEV static __device__ __forceinline__

typedef unsigned short u16;
typedef unsigned int u32;
typedef __attribute__((ext_vector_type(8))) short short8;
typedef __attribute__((ext_vector_type(8))) __bf16 bf16x8;
typedef __attribute__((ext_vector_type(4))) float f32x4;

DEV u16 f2bf(float f) {
  u32 u = __builtin_bit_cast(u32, f);
  u32 r = (u + 0x7fffu + ((u >> 16) & 1u)) >> 16;
  return (u16)r;
}
DEV float bf2f(u16 h) { u32 u = ((u32)h) << 16; return __builtin_bit_cast(float, u); }

// ---------------- weight transpose + cast: src fp32 (K,N) -> dst bf16 (N,K) ----------------
__global__ __launch_bounds__(256) void k_tcast(const float* __restrict__ src, u16* __restrict__ dst,
                                               int K, int N, size_t sStride, size_t dStride) {
  __shared__ float tl[32][33];
  int tx = threadIdx.x, ty = threadIdx.y;
  int n0 = blockIdx.x * 32, k0 = blockIdx.y * 32;
  src += (size_t)blockIdx.z * sStride;
  dst += (size_t)blockIdx.z * dStride;
#pragma unroll
  for (int i = 0; i < 4; ++i)
    tl[ty + i * 8][tx] = src[(size_t)(k0 + ty + i * 8) * N + n0 + tx];
  __syncthreads();
#pragma unroll
  for (int i = 0; i < 4; ++i)
    dst[(size_t)(n0 + ty + i * 8) * K + k0 + tx] = f2bf(tl[tx][ty + i * 8]);
}

// ---------------- patch extraction: x (B,224,224,3) -> pA bf16 (6272, 768) ----------------
__global__ __launch_bounds__(256) void k_patch_extract(const float* __restrict__ x, u16* __restrict__ pA) {
  int idx = blockIdx.x * 256 + threadIdx.x;  // < 6272*768
  int token = idx / 768, kk = idx - token * 768;
  int b = token / 196, t = token - b * 196;
  int gy = t / 14, gx = t - gy * 14;
  int py = kk / 48, rem = kk - py * 48;
  int px = rem / 3, ch = rem - px * 3;
  size_t s = ((size_t)(b * 224 + gy * 16 + py) * 224 + (gx * 16 + px)) * 3 + ch;
  pA[idx] = f2bf(x[s]);
}

// ---------------- LayerNorm: h fp32 (6272,384) -> z bf16, one wave per token ----------------
__global__ __launch_bounds__(256) void k_ln(const float* __restrict__ h, u16* __restrict__ z,
                                            const float* __restrict__ sc, const float* __restrict__ bi) {
  int wave = threadIdx.x >> 6, lane = threadIdx.x & 63;
  int token = blockIdx.x * 4 + wave;
  const float* hp = h + (size_t)token * 384;
  float v[6];
  float sum = 0.f, sq = 0.f;
#pragma unroll
  for (int j = 0; j < 6; ++j) { v[j] = hp[j * 64 + lane]; sum += v[j]; sq += v[j] * v[j]; }
#pragma unroll
  for (int o = 1; o < 64; o <<= 1) { sum += __shfl_xor(sum, o); sq += __shfl_xor(sq, o); }
  float mean = sum * (1.f / 384.f);
  float var = sq * (1.f / 384.f) - mean * mean;
  float rstd = rsqrtf(var + 1e-6f);
  u16* zp = z + (size_t)token * 384;
#pragma unroll
  for (int j = 0; j < 6; ++j) {
    int c = j * 64 + lane;
    zp[c] = f2bf((v[j] - mean) * rstd * sc[c] + bi[c]);
  }
}

// ---------------- GEMM: C = A(M,K)bf16 * BT(N,K)bf16, 128x128 tile, 4 waves ----------------
// MODE 0: out0 fp32 = acc + bias0[n] + res[(m%196)*384+n]          (patch embed + pos)
// MODE 1: n<384 -> out0 = acc+bias0[n]; else out1 = sigmoid(acc+bias1[n-384])  (u,g)
// MODE 2: outb bf16 = gelu_tanh(acc + bias0[n])                    (MLP1)
// MODE 3: out0 fp32 = res[m*384+n] + acc + bias0[n]                (MLP2 + residual)
template <int MODE>
__global__ __launch_bounds__(256) void k_gemm(const u16* __restrict__ A, const u16* __restrict__ BT,
                                              int K, int N,
                                              const float* __restrict__ bias0, const float* __restrict__ bias1,
                                              float* __restrict__ out0, float* __restrict__ out1,
                                              u16* __restrict__ outb, const float* __restrict__ res) {
  __shared__ u16 As[128 * 32];
  __shared__ u16 Bs[128 * 32];
  const int tid = threadIdx.x;
  const int tm = blockIdx.y * 128, tn = blockIdx.x * 128;
  const int lane = tid & 63, wave = tid >> 6;
  const int wy = (wave >> 1) * 64, wx = (wave & 1) * 64;
  const int quad = lane >> 4, r15 = lane & 15;
  const int rowA = tid >> 2, offA = (tid & 3) * 8;
  f32x4 acc[4][4] = {};
  for (int k0 = 0; k0 < K; k0 += 32) {
#pragma unroll
    for (int st = 0; st < 2; ++st) {
      int row = rowA + st * 64;
      *(short8*)&As[row * 32 + offA] = *(const short8*)(A + (size_t)(tm + row) * K + k0 + offA);
      *(short8*)&Bs[row * 32 + offA] = *(const short8*)(BT + (size_t)(tn + row) * K + k0 + offA);
    }
    __syncthreads();
    bf16x8 af[4], bw[4];
#pragma unroll
    for (int i = 0; i < 4; ++i) af[i] = *(const bf16x8*)&As[(wy + i * 16 + r15) * 32 + quad * 8];
#pragma unroll
    for (int j = 0; j < 4; ++j) bw[j] = *(const bf16x8*)&Bs[(wx + j * 16 + r15) * 32 + quad * 8];
#pragma unroll
    for (int i = 0; i < 4; ++i)
#pragma unroll
      for (int j = 0; j < 4; ++j)
        acc[i][j] = __builtin_amdgcn_mfma_f32_16x16x32_bf16(af[i], bw[j], acc[i][j], 0, 0, 0);
    __syncthreads();
  }
#pragma unroll
  for (int i = 0; i < 4; ++i) {
#pragma unroll
    for (int j = 0; j < 4; ++j) {
#pragma unroll
      for (int rr = 0; rr < 4; ++rr) {
        int m = tm + wy + i * 16 + quad * 4 + rr;
        int n = tn + wx + j * 16 + r15;
        float v = acc[i][j][rr];
        if (MODE == 0) {
          v += bias0[n] + res[(size_t)(m % 196) * 384 + n];
          out0[(size_t)m * N + n] = v;
        } else if (MODE == 1) {
          if (n < 384) {
            out0[(size_t)m * 384 + n] = v + bias0[n];
          } else {
            float t = v + bias1[n - 384];
            out1[(size_t)m * 384 + (n - 384)] = 1.f / (1.f + expf(-t));
          }
        } else if (MODE == 2) {
          v += bias0[n];
          float gl = 0.5f * v * (1.f + tanhf(0.7978845608028654f * (v + 0.044715f * v * v * v)));
          outb[(size_t)m * N + n] = f2bf(gl);
        } else {
          out0[(size_t)m * 384 + n] = res[(size_t)m * 384 + n] + v + bias0[n];
        }
      }
    }
  }
}

// ---------------- gated depthwise-conv recurrence, T=8, fused; h += s ----------------
// block: (b, channel-group of 32); thread: fixed channel c, pixels p = pg + 8k
__global__ __launch_bounds__(256) void k_recur(float* __restrict__ h, const float* __restrict__ ubuf,
                                               const float* __restrict__ gbuf, const float* __restrict__ kd) {
  __shared__ float sb[16 * 16 * 32];  // [y+1][x+1][c], zero halo
  const int tid = threadIdx.x;
  const int b = blockIdx.x, cg = blockIdx.y;
  const int c = tid & 31, pg = tid >> 5;
  const int cfull = cg * 32 + c;
  float kw[9];
#pragma unroll
  for (int q = 0; q < 9; ++q) kw[q] = kd[q * 384 + cfull];
  float gr[25], ur[25], sr[25];
#pragma unroll
  for (int kk = 0; kk < 25; ++kk) {
    int p = pg + kk * 8;
    bool ok = p < 196;
    size_t a = (size_t)(b * 196 + (ok ? p : 0)) * 384 + cfull;
    gr[kk] = ok ? gbuf[a] : 0.f;
    ur[kk] = ok ? ubuf[a] : 0.f;
    sr[kk] = 0.f;
  }
  for (int i = tid; i < 16 * 16 * 32; i += 256) sb[i] = 0.f;
  __syncthreads();
  for (int t = 0; t < 8; ++t) {
#pragma unroll
    for (int kk = 0; kk < 25; ++kk) {
      int p = pg + kk * 8;
      if (p < 196) {
        int y = p / 14, x = p - y * 14;
        int base = (y * 16 + x) * 32 + c;
        float conv = 0.f;
#pragma unroll
        for (int dy = 0; dy < 3; ++dy)
#pragma unroll
          for (int dx = 0; dx < 3; ++dx)
            conv += kw[dy * 3 + dx] * sb[base + (dy * 16 + dx) * 32];
        sr[kk] = gr[kk] * conv + (1.f - gr[kk]) * ur[kk];
      }
    }
    __syncthreads();
#pragma unroll
    for (int kk = 0; kk < 25; ++kk) {
      int p = pg + kk * 8;
      if (p < 196) {
        int y = p / 14, x = p - y * 14;
        sb[((y + 1) * 16 + (x + 1)) * 32 + c] = sr[kk];
      }
    }
    __syncthreads();
  }
#pragma unroll
  for (int kk = 0; kk < 25; ++kk) {
    int p = pg + kk * 8;
    if (p < 196) {
      size_t a = (size_t)(b * 196 + p) * 384 + cfull;
      h[a] += sr[kk];
    }
  }
}

// ---------------- final: per-b max-pool over 196 tokens of zf, then head GEMV ----------------
__global__ __launch_bounds__(256) void k_final(const u16* __restrict__ zf, const float* __restrict__ hw,
                                               const float* __restrict__ hb, float* __restrict__ out) {
  __shared__ float pooled[384];
  int b = blockIdx.x, tid = threadIdx.x;
  for (int c = tid; c < 384; c += 256) {
    float mx = -1e30f;
    const u16* zp = zf + (size_t)b * 196 * 384 + c;
    for (int t = 0; t < 196; ++t) mx = fmaxf(mx, bf2f(zp[t * 384]));
    pooled[c] = mx;
  }
  __syncthreads();
  for (int n = tid; n < 1000; n += 256) {
    float acc = hb[n];
    for (int k = 0; k < 384; ++k) acc += pooled[k] * hw[(size_t)k * 1000 + n];
    out[(size_t)b * 1000 + n] = acc;
  }
}

extern "C" void kernel_launch(void* const* d_in, const int* in_sizes, int n_in,
                              void* d_out, int out_size, void* d_ws, size_t ws_size,
                              hipStream_t stream) {
  const float* x       = (const float*)d_in[0];
  const float* patch_w = (const float*)d_in[1];
  const float* patch_b = (const float*)d_in[2];
  const float* pos     = (const float*)d_in[3];
  const float* ln1_s   = (const float*)d_in[4];
  const float* ln1_b   = (const float*)d_in[5];
  const float* w_in    = (const float*)d_in[6];
  const float* b_in    = (const float*)d_in[7];
  const float* w_g     = (const float*)d_in[8];
  const float* b_g     = (const float*)d_in[9];
  const float* k_dw    = (const float*)d_in[10];
  const float* ln2_s   = (const float*)d_in[11];
  const float* ln2_b   = (const float*)d_in[12];
  const float* w1      = (const float*)d_in[13];
  const float* b1      = (const float*)d_in[14];
  const float* w2      = (const float*)d_in[15];
  const float* b2      = (const float*)d_in[16];
  const float* lnf_s   = (const float*)d_in[17];
  const float* lnf_b   = (const float*)d_in[18];
  const float* head_w  = (const float*)d_in[19];
  const float* head_b  = (const float*)d_in[20];
  float* out = (float*)d_out;

  const size_t M = 6272;
  const size_t SZ_TOK = M * 384;               // 2408448
  const size_t SZ_HID = M * 1536;              // 9633792
  const size_t WT_ELEMS = 17989632;            // patchT + 12*(ugT + w1T + w2T)
  const size_t NEED = SZ_TOK * 4 * 3 + SZ_TOK * 2 + SZ_HID * 2 + WT_ELEMS * 2;
  if (ws_size < NEED) return;

  char* ws = (char*)d_ws;
  float* h = (float*)ws;   ws += SZ_TOK * 4;
  float* u = (float*)ws;   ws += SZ_TOK * 4;
  float* g = (float*)ws;   ws += SZ_TOK * 4;
  u16* z   = (u16*)ws;     ws += SZ_TOK * 2;
  u16* hid = (u16*)ws;     ws += SZ_HID * 2;
  u16* pA  = hid;          // alias: patch A-matrix (M*768) fits in hid (M*1536), used before hid
  u16* wT  = (u16*)ws;

  // wT layout (elems): patchT[294912]; per d: WiT[147456] WgT[147456] w1T[589824] w2T[589824]
  const size_t PER_D = 1474560;
  u16* patchT = wT;
  u16* ugT0 = wT + 294912;
  u16* w1T0 = wT + 294912 + 294912;
  u16* w2T0 = wT + 294912 + 294912 + 589824;

  dim3 tb(32, 8);
  k_tcast<<<dim3(12, 24, 1), tb, 0, stream>>>(patch_w, patchT, 768, 384, (size_t)0, (size_t)0);
  k_tcast<<<dim3(12, 12, 12), tb, 0, stream>>>(w_in, ugT0, 384, 384, (size_t)147456, PER_D);
  k_tcast<<<dim3(12, 12, 12), tb, 0, stream>>>(w_g, ugT0 + 147456, 384, 384, (size_t)147456, PER_D);
  k_tcast<<<dim3(48, 12, 12), tb, 0, stream>>>(w1, w1T0, 384, 1536, (size_t)589824, PER_D);
  k_tcast<<<dim3(12, 48, 12), tb, 0, stream>>>(w2, w2T0, 1536, 384, (size_t)589824, PER_D);

  k_patch_extract<<<18816, 256, 0, stream>>>(x, pA);

  // patch embed GEMM: h = pA @ patch_w + patch_b + pos
  k_gemm<0><<<dim3(3, 49), 256, 0, stream>>>(pA, patchT, 768, 384, patch_b, nullptr, h, nullptr, nullptr, pos);

  for (int d = 0; d < 12; ++d) {
    const u16* ugT = ugT0 + (size_t)d * PER_D;
    const u16* w1T = w1T0 + (size_t)d * PER_D;
    const u16* w2T = w2T0 + (size_t)d * PER_D;
    k_ln<<<1568, 256, 0, stream>>>(h, z, ln1_s + (size_t)d * 384, ln1_b + (size_t)d * 384);
    k_gemm<1><<<dim3(6, 49), 256, 0, stream>>>(z, ugT, 384, 768, b_in + (size_t)d * 384,
                                               b_g + (size_t)d * 384, u, g, nullptr, nullptr);
    k_recur<<<dim3(32, 12), 256, 0, stream>>>(h, u, g, k_dw + (size_t)d * 3456);
    k_ln<<<1568, 256, 0, stream>>>(h, z, ln2_s + (size_t)d * 384, ln2_b + (size_t)d * 384);
    k_gemm<2><<<dim3(12, 49), 256, 0, stream>>>(z, w1T, 384, 1536, b1 + (size_t)d * 1536,
                                                nullptr, nullptr, nullptr, hid, nullptr);
    k_gemm<3><<<dim3(3, 49), 256, 0, stream>>>(hid, w2T, 1536, 384, b2 + (size_t)d * 384,
                                               nullptr, h, nullptr, nullptr, h);
  }

  k_ln<<<1568, 256, 0, stream>>>(h, z, lnf_s, lnf_b);
  k_final<<<32, 256, 0, stream>>>(z, head_w, head_b, out);
}

// Round 2
// 1872.543 us; speedup vs baseline: 1.0286x; 1.0286x over previous
//
#include <hip/hip_runtime.h>
#include <cstdint>
#include <cstddef>

#define DEV static __device__ __forceinline__

typedef unsigned short u16;
typedef unsigned int u32;
typedef __attribute__((ext_vector_type(8))) short short8;
typedef __attribute__((ext_vector_type(8))) __bf16 bf16x8;
typedef __attribute__((ext_vector_type(4))) float f32x4;

DEV u16 f2bf(float f) {
  u32 u = __builtin_bit_cast(u32, f);
  u32 r = (u + 0x7fffu + ((u >> 16) & 1u)) >> 16;
  return (u16)r;
}
DEV float bf2f(u16 h) { u32 u = ((u32)h) << 16; return __builtin_bit_cast(float, u); }

// async global->LDS, 16B per lane; lds base must be wave-uniform (dest = base + lane*16)
DEV void ld_lds16(const u16* g, u16* l) {
  __builtin_amdgcn_global_load_lds((const __attribute__((address_space(1))) void*)g,
                                   (__attribute__((address_space(3))) void*)l, 16, 0, 0);
}

// ---------------- weight transpose + cast: src fp32 (K,N) -> dst bf16 (N,K) ----------------
__global__ __launch_bounds__(256) void k_tcast(const float* __restrict__ src, u16* __restrict__ dst,
                                               int K, int N, size_t sStride, size_t dStride) {
  __shared__ float tl[32][33];
  int tx = threadIdx.x, ty = threadIdx.y;
  int n0 = blockIdx.x * 32, k0 = blockIdx.y * 32;
  src += (size_t)blockIdx.z * sStride;
  dst += (size_t)blockIdx.z * dStride;
#pragma unroll
  for (int i = 0; i < 4; ++i)
    tl[ty + i * 8][tx] = src[(size_t)(k0 + ty + i * 8) * N + n0 + tx];
  __syncthreads();
#pragma unroll
  for (int i = 0; i < 4; ++i)
    dst[(size_t)(n0 + ty + i * 8) * K + k0 + tx] = f2bf(tl[tx][ty + i * 8]);
}

// ---------------- patch extraction: x (B,224,224,3) -> pA bf16 (6272, 768) ----------------
__global__ __launch_bounds__(256) void k_patch_extract(const float* __restrict__ x, u16* __restrict__ pA) {
  int idx = blockIdx.x * 256 + threadIdx.x;  // < 6272*768
  int token = idx / 768, kk = idx - token * 768;
  int b = token / 196, t = token - b * 196;
  int gy = t / 14, gx = t - gy * 14;
  int py = kk / 48, rem = kk - py * 48;
  int px = rem / 3, ch = rem - px * 3;
  size_t s = ((size_t)(b * 224 + gy * 16 + py) * 224 + (gx * 16 + px)) * 3 + ch;
  pA[idx] = f2bf(x[s]);
}

// ---------------- LayerNorm: h fp32 (6272,384) -> z bf16, one wave per token ----------------
__global__ __launch_bounds__(256) void k_ln(const float* __restrict__ h, u16* __restrict__ z,
                                            const float* __restrict__ sc, const float* __restrict__ bi) {
  int wave = threadIdx.x >> 6, lane = threadIdx.x & 63;
  int token = blockIdx.x * 4 + wave;
  const float* hp = h + (size_t)token * 384;
  float v[6];
  float sum = 0.f, sq = 0.f;
#pragma unroll
  for (int j = 0; j < 6; ++j) { v[j] = hp[j * 64 + lane]; sum += v[j]; sq += v[j] * v[j]; }
#pragma unroll
  for (int o = 1; o < 64; o <<= 1) { sum += __shfl_xor(sum, o); sq += __shfl_xor(sq, o); }
  float mean = sum * (1.f / 384.f);
  float var = sq * (1.f / 384.f) - mean * mean;
  float rstd = rsqrtf(var + 1e-6f);
  u16* zp = z + (size_t)token * 384;
#pragma unroll
  for (int j = 0; j < 6; ++j) {
    int c = j * 64 + lane;
    zp[c] = f2bf((v[j] - mean) * rstd * sc[c] + bi[c]);
  }
}

// ---------------- GEMM: C = A(M,K)bf16 * BT(N,K)bf16, 128x128 tile, 4 waves ----------------
// MODE 0: out0 fp32 = acc + bias0[n] + res[(m%196)*384+n]          (patch embed + pos)
// MODE 1: n<384 -> out0 = acc+bias0[n]; else out1 = sigmoid(acc+bias1[n-384])  (u,g)
// MODE 2: outb bf16 = gelu_tanh(acc + bias0[n])                    (MLP1)
// MODE 3: out0 fp32 = res[m*384+n] + acc + bias0[n]                (MLP2 + residual)
template <int MODE>
__global__ __launch_bounds__(256) void k_gemm(const u16* __restrict__ A, const u16* __restrict__ BT,
                                              int K, int N,
                                              const float* __restrict__ bias0, const float* __restrict__ bias1,
                                              float* __restrict__ out0, float* __restrict__ out1,
                                              u16* __restrict__ outb, const float* __restrict__ res) {
  // LDS layout is lane-contiguous: byte addr = tid*16 (+ st*4096) -> row-major 128x32 u16
  __shared__ alignas(16) u16 As[128 * 32];
  __shared__ alignas(16) u16 Bs[128 * 32];
  const int tid = threadIdx.x;
  const int tm = blockIdx.y * 128, tn = blockIdx.x * 128;
  const int lane = tid & 63, wave = tid >> 6;
  const int wy = (wave >> 1) * 64, wx = (wave & 1) * 64;
  const int quad = lane >> 4, r15 = lane & 15;
  const int rowA = tid >> 2, offA = (tid & 3) * 8;
  const u16* Ab = A + (size_t)(tm + rowA) * K + offA;
  const u16* Bb = BT + (size_t)(tn + rowA) * K + offA;
  u16* AsW = As + wave * 512;  // wave-uniform LDS base (u16 elems; *2 = bytes)
  u16* BsW = Bs + wave * 512;
  f32x4 acc[4][4] = {};
  for (int k0 = 0; k0 < K; k0 += 32) {
#pragma unroll
    for (int st = 0; st < 2; ++st) {
      ld_lds16(Ab + (size_t)st * 64 * K + k0, AsW + st * 2048);
      ld_lds16(Bb + (size_t)st * 64 * K + k0, BsW + st * 2048);
    }
    __syncthreads();
    bf16x8 af[4], bw[4];
#pragma unroll
    for (int i = 0; i < 4; ++i) af[i] = *(const bf16x8*)&As[(wy + i * 16 + r15) * 32 + quad * 8];
#pragma unroll
    for (int j = 0; j < 4; ++j) bw[j] = *(const bf16x8*)&Bs[(wx + j * 16 + r15) * 32 + quad * 8];
#pragma unroll
    for (int i = 0; i < 4; ++i)
#pragma unroll
      for (int j = 0; j < 4; ++j)
        acc[i][j] = __builtin_amdgcn_mfma_f32_16x16x32_bf16(af[i], bw[j], acc[i][j], 0, 0, 0);
    __syncthreads();
  }
#pragma unroll
  for (int i = 0; i < 4; ++i) {
#pragma unroll
    for (int j = 0; j < 4; ++j) {
#pragma unroll
      for (int rr = 0; rr < 4; ++rr) {
        int m = tm + wy + i * 16 + quad * 4 + rr;
        int n = tn + wx + j * 16 + r15;
        float v = acc[i][j][rr];
        if (MODE == 0) {
          v += bias0[n] + res[(size_t)(m % 196) * 384 + n];
          out0[(size_t)m * N + n] = v;
        } else if (MODE == 1) {
          if (n < 384) {
            out0[(size_t)m * 384 + n] = v + bias0[n];
          } else {
            float t = v + bias1[n - 384];
            out1[(size_t)m * 384 + (n - 384)] = 1.f / (1.f + expf(-t));
          }
        } else if (MODE == 2) {
          v += bias0[n];
          float gl = 0.5f * v * (1.f + tanhf(0.7978845608028654f * (v + 0.044715f * v * v * v)));
          outb[(size_t)m * N + n] = f2bf(gl);
        } else {
          out0[(size_t)m * 384 + n] = res[(size_t)m * 384 + n] + v + bias0[n];
        }
      }
    }
  }
}

// ---------------- gated depthwise-conv recurrence, T=8, fused; h += s ----------------
__global__ __launch_bounds__(256) void k_recur(float* __restrict__ h, const float* __restrict__ ubuf,
                                               const float* __restrict__ gbuf, const float* __restrict__ kd) {
  __shared__ float sb[16 * 16 * 32];  // [y+1][x+1][c], zero halo
  const int tid = threadIdx.x;
  const int b = blockIdx.x, cg = blockIdx.y;
  const int c = tid & 31, pg = tid >> 5;
  const int cfull = cg * 32 + c;
  float kw[9];
#pragma unroll
  for (int q = 0; q < 9; ++q) kw[q] = kd[q * 384 + cfull];
  float gr[25], ur[25], sr[25];
#pragma unroll
  for (int kk = 0; kk < 25; ++kk) {
    int p = pg + kk * 8;
    bool ok = p < 196;
    size_t a = (size_t)(b * 196 + (ok ? p : 0)) * 384 + cfull;
    gr[kk] = ok ? gbuf[a] : 0.f;
    ur[kk] = ok ? ubuf[a] : 0.f;
    sr[kk] = 0.f;
  }
  for (int i = tid; i < 16 * 16 * 32; i += 256) sb[i] = 0.f;
  __syncthreads();
  for (int t = 0; t < 8; ++t) {
#pragma unroll
    for (int kk = 0; kk < 25; ++kk) {
      int p = pg + kk * 8;
      if (p < 196) {
        int y = p / 14, x = p - y * 14;
        int base = (y * 16 + x) * 32 + c;
        float conv = 0.f;
#pragma unroll
        for (int dy = 0; dy < 3; ++dy)
#pragma unroll
          for (int dx = 0; dx < 3; ++dx)
            conv += kw[dy * 3 + dx] * sb[base + (dy * 16 + dx) * 32];
        sr[kk] = gr[kk] * conv + (1.f - gr[kk]) * ur[kk];
      }
    }
    __syncthreads();
#pragma unroll
    for (int kk = 0; kk < 25; ++kk) {
      int p = pg + kk * 8;
      if (p < 196) {
        int y = p / 14, x = p - y * 14;
        sb[((y + 1) * 16 + (x + 1)) * 32 + c] = sr[kk];
      }
    }
    __syncthreads();
  }
#pragma unroll
  for (int kk = 0; kk < 25; ++kk) {
    int p = pg + kk * 8;
    if (p < 196) {
      size_t a = (size_t)(b * 196 + p) * 384 + cfull;
      h[a] += sr[kk];
    }
  }
}

// ---------------- pool: per-(b) spatial max over 196 tokens -> pooled fp32 (32,384) ----------------
__global__ __launch_bounds__(384) void k_pool(const u16* __restrict__ zf, float* __restrict__ pooled) {
  int b = blockIdx.x, c = threadIdx.x;
  const u16* zp = zf + (size_t)b * 196 * 384 + c;
  float mx = -3.4e38f;
#pragma unroll 4
  for (int t = 0; t < 196; ++t) mx = fmaxf(mx, bf2f(zp[t * 384]));
  pooled[b * 384 + c] = mx;
}

// ---------------- head GEMV: out(32,1000) = pooled(32,384) @ hw(384,1000) + hb ----------------
__global__ __launch_bounds__(256) void k_head(const float* __restrict__ pooled, const float* __restrict__ hw,
                                              const float* __restrict__ hb, float* __restrict__ out) {
  int idx = blockIdx.x * 256 + threadIdx.x;  // 32000
  int b = idx / 1000, n = idx - b * 1000;
  const float* pp = pooled + b * 384;
  float acc = hb[n];
#pragma unroll 4
  for (int k = 0; k < 384; ++k) acc += pp[k] * hw[(size_t)k * 1000 + n];
  out[idx] = acc;
}

extern "C" void kernel_launch(void* const* d_in, const int* in_sizes, int n_in,
                              void* d_out, int out_size, void* d_ws, size_t ws_size,
                              hipStream_t stream) {
  const float* x       = (const float*)d_in[0];
  const float* patch_w = (const float*)d_in[1];
  const float* patch_b = (const float*)d_in[2];
  const float* pos     = (const float*)d_in[3];
  const float* ln1_s   = (const float*)d_in[4];
  const float* ln1_b   = (const float*)d_in[5];
  const float* w_in    = (const float*)d_in[6];
  const float* b_in    = (const float*)d_in[7];
  const float* w_g     = (const float*)d_in[8];
  const float* b_g     = (const float*)d_in[9];
  const float* k_dw    = (const float*)d_in[10];
  const float* ln2_s   = (const float*)d_in[11];
  const float* ln2_b   = (const float*)d_in[12];
  const float* w1      = (const float*)d_in[13];
  const float* b1      = (const float*)d_in[14];
  const float* w2      = (const float*)d_in[15];
  const float* b2      = (const float*)d_in[16];
  const float* lnf_s   = (const float*)d_in[17];
  const float* lnf_b   = (const float*)d_in[18];
  const float* head_w  = (const float*)d_in[19];
  const float* head_b  = (const float*)d_in[20];
  float* out = (float*)d_out;

  const size_t M = 6272;
  const size_t SZ_TOK = M * 384;               // 2408448
  const size_t SZ_HID = M * 1536;              // 9633792
  const size_t WT_ELEMS = 17989632;            // patchT + 12*(ugT + w1T + w2T)
  const size_t NEED = SZ_TOK * 4 * 3 + SZ_TOK * 2 + SZ_HID * 2 + WT_ELEMS * 2;
  if (ws_size < NEED) return;

  char* ws = (char*)d_ws;
  float* h = (float*)ws;   ws += SZ_TOK * 4;
  float* u = (float*)ws;   ws += SZ_TOK * 4;
  float* g = (float*)ws;   ws += SZ_TOK * 4;
  u16* z   = (u16*)ws;     ws += SZ_TOK * 2;
  u16* hid = (u16*)ws;     ws += SZ_HID * 2;
  u16* pA  = hid;          // alias: patch A-matrix (M*768) fits in hid (M*1536), used before hid
  u16* wT  = (u16*)ws;
  float* pooled = u;       // reuse u buffer at the end (free after last recur)

  // wT layout (elems): patchT[294912]; per d: WiT[147456] WgT[147456] w1T[589824] w2T[589824]
  const size_t PER_D = 1474560;
  u16* patchT = wT;
  u16* ugT0 = wT + 294912;
  u16* w1T0 = wT + 294912 + 294912;
  u16* w2T0 = wT + 294912 + 294912 + 589824;

  dim3 tb(32, 8);
  k_tcast<<<dim3(12, 24, 1), tb, 0, stream>>>(patch_w, patchT, 768, 384, (size_t)0, (size_t)0);
  k_tcast<<<dim3(12, 12, 12), tb, 0, stream>>>(w_in, ugT0, 384, 384, (size_t)147456, PER_D);
  k_tcast<<<dim3(12, 12, 12), tb, 0, stream>>>(w_g, ugT0 + 147456, 384, 384, (size_t)147456, PER_D);
  k_tcast<<<dim3(48, 12, 12), tb, 0, stream>>>(w1, w1T0, 384, 1536, (size_t)589824, PER_D);
  k_tcast<<<dim3(12, 48, 12), tb, 0, stream>>>(w2, w2T0, 1536, 384, (size_t)589824, PER_D);

  k_patch_extract<<<18816, 256, 0, stream>>>(x, pA);

  // patch embed GEMM: h = pA @ patch_w + patch_b + pos
  k_gemm<0><<<dim3(3, 49), 256, 0, stream>>>(pA, patchT, 768, 384, patch_b, nullptr, h, nullptr, nullptr, pos);

  for (int d = 0; d < 12; ++d) {
    const u16* ugT = ugT0 + (size_t)d * PER_D;
    const u16* w1T = w1T0 + (size_t)d * PER_D;
    const u16* w2T = w2T0 + (size_t)d * PER_D;
    k_ln<<<1568, 256, 0, stream>>>(h, z, ln1_s + (size_t)d * 384, ln1_b + (size_t)d * 384);
    k_gemm<1><<<dim3(6, 49), 256, 0, stream>>>(z, ugT, 384, 768, b_in + (size_t)d * 384,
                                               b_g + (size_t)d * 384, u, g, nullptr, nullptr);
    k_recur<<<dim3(32, 12), 256, 0, stream>>>(h, u, g, k_dw + (size_t)d * 3456);
    k_ln<<<1568, 256, 0, stream>>>(h, z, ln2_s + (size_t)d * 384, ln2_b + (size_t)d * 384);
    k_gemm<2><<<dim3(12, 49), 256, 0, stream>>>(z, w1T, 384, 1536, b1 + (size_t)d * 1536,
                                                nullptr, nullptr, nullptr, hid, nullptr);
    k_gemm<3><<<dim3(3, 49), 256, 0, stream>>>(hid, w2T, 1536, 384, b2 + (size_t)d * 384,
                                               nullptr, h, nullptr, nullptr, h);
  }

  k_ln<<<1568, 256, 0, stream>>>(h, z, lnf_s, lnf_b);
  k_pool<<<32, 384, 0, stream>>>(z, pooled);
  k_head<<<125, 256, 0, stream>>>(pooled, head_w, head_b, out);
}

// Round 3
// 1595.560 us; speedup vs baseline: 1.2072x; 1.1736x over previous
//
#include <hip/hip_runtime.h>
#include <cstdint>
#include <cstddef>

#define DEV static __device__ __forceinline__

typedef unsigned short u16;
typedef unsigned int u32;
typedef __attribute__((ext_vector_type(8))) short short8;
typedef __attribute__((ext_vector_type(8))) __bf16 bf16x8;
typedef __attribute__((ext_vector_type(4))) float f32x4;

DEV u16 f2bf(float f) {
  u32 u = __builtin_bit_cast(u32, f);
  u32 r = (u + 0x7fffu + ((u >> 16) & 1u)) >> 16;
  return (u16)r;
}
DEV float bf2f(u16 h) { u32 u = ((u32)h) << 16; return __builtin_bit_cast(float, u); }

// async global->LDS, 16B per lane; lds base must be wave-uniform (dest = base + lane*16)
DEV void ld_lds16(const u16* g, u16* l) {
  __builtin_amdgcn_global_load_lds((const __attribute__((address_space(1))) void*)g,
                                   (__attribute__((address_space(3))) void*)l, 16, 0, 0);
}

// ---------------- weight transpose + cast: src fp32 (K,N) -> dst bf16 (N,K) ----------------
__global__ __launch_bounds__(256) void k_tcast(const float* __restrict__ src, u16* __restrict__ dst,
                                               int K, int N, size_t sStride, size_t dStride) {
  __shared__ float tl[32][33];
  int tx = threadIdx.x, ty = threadIdx.y;
  int n0 = blockIdx.x * 32, k0 = blockIdx.y * 32;
  src += (size_t)blockIdx.z * sStride;
  dst += (size_t)blockIdx.z * dStride;
#pragma unroll
  for (int i = 0; i < 4; ++i)
    tl[ty + i * 8][tx] = src[(size_t)(k0 + ty + i * 8) * N + n0 + tx];
  __syncthreads();
#pragma unroll
  for (int i = 0; i < 4; ++i)
    dst[(size_t)(n0 + ty + i * 8) * K + k0 + tx] = f2bf(tl[tx][ty + i * 8]);
}

// ---------------- fp32 transpose with N-guard: src (K,N) -> dst (N,K); K % 32 == 0 ----------------
__global__ __launch_bounds__(256) void k_tcastf(const float* __restrict__ src, float* __restrict__ dst,
                                                int K, int N) {
  __shared__ float tl[32][33];
  int tx = threadIdx.x, ty = threadIdx.y;
  int n0 = blockIdx.x * 32, k0 = blockIdx.y * 32;
#pragma unroll
  for (int i = 0; i < 4; ++i)
    if (n0 + tx < N) tl[ty + i * 8][tx] = src[(size_t)(k0 + ty + i * 8) * N + n0 + tx];
  __syncthreads();
#pragma unroll
  for (int i = 0; i < 4; ++i)
    if (n0 + ty + i * 8 < N) dst[(size_t)(n0 + ty + i * 8) * K + k0 + tx] = tl[tx][ty + i * 8];
}

// ---------------- patch extraction: x (B,224,224,3) -> pA bf16 (6272, 768) ----------------
__global__ __launch_bounds__(256) void k_patch_extract(const float* __restrict__ x, u16* __restrict__ pA) {
  int idx = blockIdx.x * 256 + threadIdx.x;  // < 6272*768
  int token = idx / 768, kk = idx - token * 768;
  int b = token / 196, t = token - b * 196;
  int gy = t / 14, gx = t - gy * 14;
  int py = kk / 48, rem = kk - py * 48;
  int px = rem / 3, ch = rem - px * 3;
  size_t s = ((size_t)(b * 224 + gy * 16 + py) * 224 + (gx * 16 + px)) * 3 + ch;
  pA[idx] = f2bf(x[s]);
}

// ---------------- LayerNorm: h fp32 (6272,384) -> z bf16, one wave per token ----------------
__global__ __launch_bounds__(256) void k_ln(const float* __restrict__ h, u16* __restrict__ z,
                                            const float* __restrict__ sc, const float* __restrict__ bi) {
  int wave = threadIdx.x >> 6, lane = threadIdx.x & 63;
  int token = blockIdx.x * 4 + wave;
  const float* hp = h + (size_t)token * 384;
  float v[6];
  float sum = 0.f, sq = 0.f;
#pragma unroll
  for (int j = 0; j < 6; ++j) { v[j] = hp[j * 64 + lane]; sum += v[j]; sq += v[j] * v[j]; }
#pragma unroll
  for (int o = 1; o < 64; o <<= 1) { sum += __shfl_xor(sum, o); sq += __shfl_xor(sq, o); }
  float mean = sum * (1.f / 384.f);
  float var = sq * (1.f / 384.f) - mean * mean;
  float rstd = rsqrtf(var + 1e-6f);
  u16* zp = z + (size_t)token * 384;
#pragma unroll
  for (int j = 0; j < 6; ++j) {
    int c = j * 64 + lane;
    zp[c] = f2bf((v[j] - mean) * rstd * sc[c] + bi[c]);
  }
}

// ---------------- GEMM: C = A(M,K)bf16 * BT(N,K)bf16, (MI*32)x128 tile, 4 waves ----------------
// MI=4: 128x128 tile (wave = 64x64);  MI=2: 64x128 tile (wave = 32x64)
// MODE 0: out0 fp32 = acc + bias0[n] + res[(m%196)*384+n]          (patch embed + pos)
// MODE 1: n<384 -> out0 = acc+bias0[n]; else out1 = sigmoid(acc+bias1[n-384])  (u,g)
// MODE 2: outb bf16 = gelu_tanh(acc + bias0[n])                    (MLP1)
// MODE 3: out0 fp32 = res[m*384+n] + acc + bias0[n]                (MLP2 + residual)
template <int MODE, int MI>
__global__ __launch_bounds__(256) void k_gemm(const u16* __restrict__ A, const u16* __restrict__ BT,
                                              int K, int N,
                                              const float* __restrict__ bias0, const float* __restrict__ bias1,
                                              float* __restrict__ out0, float* __restrict__ out1,
                                              u16* __restrict__ outb, const float* __restrict__ res) {
  constexpr int TM = MI * 32;
  // LDS layout is lane-contiguous: byte addr = tid*16 (+ st*4096) -> row-major (rows x 32) u16
  __shared__ alignas(16) u16 As[TM * 32];
  __shared__ alignas(16) u16 Bs[128 * 32];
  const int tid = threadIdx.x;
  const int tm = blockIdx.y * TM, tn = blockIdx.x * 128;
  const int lane = tid & 63, wave = tid >> 6;
  const int wy = (wave >> 1) * (MI * 16), wx = (wave & 1) * 64;
  const int quad = lane >> 4, r15 = lane & 15;
  const int rowA = tid >> 2, offA = (tid & 3) * 8;
  const u16* Ab = A + (size_t)(tm + rowA) * K + offA;
  const u16* Bb = BT + (size_t)(tn + rowA) * K + offA;
  u16* AsW = As + wave * 512;  // wave-uniform LDS base (u16 elems; *2 = bytes)
  u16* BsW = Bs + wave * 512;
  f32x4 acc[MI][4] = {};
  for (int k0 = 0; k0 < K; k0 += 32) {
#pragma unroll
    for (int st = 0; st < TM / 64; ++st)
      ld_lds16(Ab + (size_t)st * 64 * K + k0, AsW + st * 2048);
#pragma unroll
    for (int st = 0; st < 2; ++st)
      ld_lds16(Bb + (size_t)st * 64 * K + k0, BsW + st * 2048);
    __syncthreads();
    bf16x8 af[MI], bw[4];
#pragma unroll
    for (int i = 0; i < MI; ++i) af[i] = *(const bf16x8*)&As[(wy + i * 16 + r15) * 32 + quad * 8];
#pragma unroll
    for (int j = 0; j < 4; ++j) bw[j] = *(const bf16x8*)&Bs[(wx + j * 16 + r15) * 32 + quad * 8];
#pragma unroll
    for (int i = 0; i < MI; ++i)
#pragma unroll
      for (int j = 0; j < 4; ++j)
        acc[i][j] = __builtin_amdgcn_mfma_f32_16x16x32_bf16(af[i], bw[j], acc[i][j], 0, 0, 0);
    __syncthreads();
  }
#pragma unroll
  for (int i = 0; i < MI; ++i) {
#pragma unroll
    for (int j = 0; j < 4; ++j) {
#pragma unroll
      for (int rr = 0; rr < 4; ++rr) {
        int m = tm + wy + i * 16 + quad * 4 + rr;
        int n = tn + wx + j * 16 + r15;
        float v = acc[i][j][rr];
        if (MODE == 0) {
          v += bias0[n] + res[(size_t)(m % 196) * 384 + n];
          out0[(size_t)m * N + n] = v;
        } else if (MODE == 1) {
          if (n < 384) {
            out0[(size_t)m * 384 + n] = v + bias0[n];
          } else {
            float t = v + bias1[n - 384];
            out1[(size_t)m * 384 + (n - 384)] = 1.f / (1.f + expf(-t));
          }
        } else if (MODE == 2) {
          v += bias0[n];
          float gl = 0.5f * v * (1.f + tanhf(0.7978845608028654f * (v + 0.044715f * v * v * v)));
          outb[(size_t)m * N + n] = f2bf(gl);
        } else {
          out0[(size_t)m * 384 + n] = res[(size_t)m * 384 + n] + v + bias0[n];
        }
      }
    }
  }
}

// ---------------- gated depthwise-conv recurrence, T=8, fused; h += s ----------------
__global__ __launch_bounds__(256) void k_recur(float* __restrict__ h, const float* __restrict__ ubuf,
                                               const float* __restrict__ gbuf, const float* __restrict__ kd) {
  __shared__ float sb[16 * 16 * 32];  // [y+1][x+1][c], zero halo
  const int tid = threadIdx.x;
  const int b = blockIdx.x, cg = blockIdx.y;
  const int c = tid & 31, pg = tid >> 5;
  const int cfull = cg * 32 + c;
  float kw[9];
#pragma unroll
  for (int q = 0; q < 9; ++q) kw[q] = kd[q * 384 + cfull];
  float gr[25], ur[25], sr[25];
#pragma unroll
  for (int kk = 0; kk < 25; ++kk) {
    int p = pg + kk * 8;
    bool ok = p < 196;
    size_t a = (size_t)(b * 196 + (ok ? p : 0)) * 384 + cfull;
    gr[kk] = ok ? gbuf[a] : 0.f;
    ur[kk] = ok ? ubuf[a] : 0.f;
    sr[kk] = 0.f;
  }
  for (int i = tid; i < 16 * 16 * 32; i += 256) sb[i] = 0.f;
  __syncthreads();
  for (int t = 0; t < 8; ++t) {
#pragma unroll
    for (int kk = 0; kk < 25; ++kk) {
      int p = pg + kk * 8;
      if (p < 196) {
        int y = p / 14, x = p - y * 14;
        int base = (y * 16 + x) * 32 + c;
        float conv = 0.f;
#pragma unroll
        for (int dy = 0; dy < 3; ++dy)
#pragma unroll
          for (int dx = 0; dx < 3; ++dx)
            conv += kw[dy * 3 + dx] * sb[base + (dy * 16 + dx) * 32];
        sr[kk] = gr[kk] * conv + (1.f - gr[kk]) * ur[kk];
      }
    }
    __syncthreads();
#pragma unroll
    for (int kk = 0; kk < 25; ++kk) {
      int p = pg + kk * 8;
      if (p < 196) {
        int y = p / 14, x = p - y * 14;
        sb[((y + 1) * 16 + (x + 1)) * 32 + c] = sr[kk];
      }
    }
    __syncthreads();
  }
#pragma unroll
  for (int kk = 0; kk < 25; ++kk) {
    int p = pg + kk * 8;
    if (p < 196) {
      size_t a = (size_t)(b * 196 + p) * 384 + cfull;
      h[a] += sr[kk];
    }
  }
}

// ---------------- pool: per-(b) spatial max over 196 tokens -> pooled fp32 (32,384) ----------------
__global__ __launch_bounds__(384) void k_pool(const u16* __restrict__ zf, float* __restrict__ pooled) {
  int b = blockIdx.x, c = threadIdx.x;
  const u16* zp = zf + (size_t)b * 196 * 384 + c;
  float mx = -3.4e38f;
  for (int t0 = 0; t0 < 196; t0 += 14) {
    float v[14];
#pragma unroll
    for (int j = 0; j < 14; ++j) v[j] = bf2f(zp[(t0 + j) * 384]);
#pragma unroll
    for (int j = 0; j < 14; ++j) mx = fmaxf(mx, v[j]);
  }
  pooled[b * 384 + c] = mx;
}

// ---------------- head GEMV: wave per (b,n); hwT is (1000,384) fp32 ----------------
__global__ __launch_bounds__(256) void k_head(const float* __restrict__ pooled, const float* __restrict__ hwT,
                                              const float* __restrict__ hb, float* __restrict__ out) {
  int w = (blockIdx.x * 256 + threadIdx.x) >> 6;  // 0..31999
  int lane = threadIdx.x & 63;
  int b = w / 1000, n = w - b * 1000;
  const float* pp = pooled + b * 384 + lane;
  const float* wp = hwT + (size_t)n * 384 + lane;
  float acc = 0.f;
#pragma unroll
  for (int j = 0; j < 6; ++j) acc += pp[j * 64] * wp[j * 64];
#pragma unroll
  for (int o = 1; o < 64; o <<= 1) acc += __shfl_xor(acc, o);
  if (lane == 0) out[w] = acc + hb[n];
}

extern "C" void kernel_launch(void* const* d_in, const int* in_sizes, int n_in,
                              void* d_out, int out_size, void* d_ws, size_t ws_size,
                              hipStream_t stream) {
  const float* x       = (const float*)d_in[0];
  const float* patch_w = (const float*)d_in[1];
  const float* patch_b = (const float*)d_in[2];
  const float* pos     = (const float*)d_in[3];
  const float* ln1_s   = (const float*)d_in[4];
  const float* ln1_b   = (const float*)d_in[5];
  const float* w_in    = (const float*)d_in[6];
  const float* b_in    = (const float*)d_in[7];
  const float* w_g     = (const float*)d_in[8];
  const float* b_g     = (const float*)d_in[9];
  const float* k_dw    = (const float*)d_in[10];
  const float* ln2_s   = (const float*)d_in[11];
  const float* ln2_b   = (const float*)d_in[12];
  const float* w1      = (const float*)d_in[13];
  const float* b1      = (const float*)d_in[14];
  const float* w2      = (const float*)d_in[15];
  const float* b2      = (const float*)d_in[16];
  const float* lnf_s   = (const float*)d_in[17];
  const float* lnf_b   = (const float*)d_in[18];
  const float* head_w  = (const float*)d_in[19];
  const float* head_b  = (const float*)d_in[20];
  float* out = (float*)d_out;

  const size_t M = 6272;
  const size_t SZ_TOK = M * 384;               // 2408448
  const size_t SZ_HID = M * 1536;              // 9633792
  const size_t WT_ELEMS = 17989632;            // patchT + 12*(ugT + w1T + w2T)
  const size_t NEED = SZ_TOK * 4 * 3 + SZ_TOK * 2 + SZ_HID * 2 + WT_ELEMS * 2;
  if (ws_size < NEED) return;

  char* ws = (char*)d_ws;
  float* h = (float*)ws;   ws += SZ_TOK * 4;
  float* u = (float*)ws;   ws += SZ_TOK * 4;
  float* g = (float*)ws;   ws += SZ_TOK * 4;
  u16* z   = (u16*)ws;     ws += SZ_TOK * 2;
  u16* hid = (u16*)ws;     ws += SZ_HID * 2;
  u16* pA  = hid;          // alias: patch A-matrix (M*768) fits in hid (M*1536), used before hid
  u16* wT  = (u16*)ws;
  float* pooled = u;       // reuse u buffer at the end (free after last recur)
  float* hwT = (float*)hid;  // reuse hid at the end (free after last gemm3); 1.536 MB << 19.3 MB

  // wT layout (elems): patchT[294912]; per d: WiT[147456] WgT[147456] w1T[589824] w2T[589824]
  const size_t PER_D = 1474560;
  u16* patchT = wT;
  u16* ugT0 = wT + 294912;
  u16* w1T0 = wT + 294912 + 294912;
  u16* w2T0 = wT + 294912 + 294912 + 589824;

  dim3 tb(32, 8);
  k_tcast<<<dim3(12, 24, 1), tb, 0, stream>>>(patch_w, patchT, 768, 384, (size_t)0, (size_t)0);
  k_tcast<<<dim3(12, 12, 12), tb, 0, stream>>>(w_in, ugT0, 384, 384, (size_t)147456, PER_D);
  k_tcast<<<dim3(12, 12, 12), tb, 0, stream>>>(w_g, ugT0 + 147456, 384, 384, (size_t)147456, PER_D);
  k_tcast<<<dim3(48, 12, 12), tb, 0, stream>>>(w1, w1T0, 384, 1536, (size_t)589824, PER_D);
  k_tcast<<<dim3(12, 48, 12), tb, 0, stream>>>(w2, w2T0, 1536, 384, (size_t)589824, PER_D);

  k_patch_extract<<<18816, 256, 0, stream>>>(x, pA);

  // patch embed GEMM: h = pA @ patch_w + patch_b + pos
  k_gemm<0, 2><<<dim3(3, 98), 256, 0, stream>>>(pA, patchT, 768, 384, patch_b, nullptr, h, nullptr, nullptr, pos);

  for (int d = 0; d < 12; ++d) {
    const u16* ugT = ugT0 + (size_t)d * PER_D;
    const u16* w1T = w1T0 + (size_t)d * PER_D;
    const u16* w2T = w2T0 + (size_t)d * PER_D;
    k_ln<<<1568, 256, 0, stream>>>(h, z, ln1_s + (size_t)d * 384, ln1_b + (size_t)d * 384);
    k_gemm<1, 2><<<dim3(6, 98), 256, 0, stream>>>(z, ugT, 384, 768, b_in + (size_t)d * 384,
                                                  b_g + (size_t)d * 384, u, g, nullptr, nullptr);
    k_recur<<<dim3(32, 12), 256, 0, stream>>>(h, u, g, k_dw + (size_t)d * 3456);
    k_ln<<<1568, 256, 0, stream>>>(h, z, ln2_s + (size_t)d * 384, ln2_b + (size_t)d * 384);
    k_gemm<2, 4><<<dim3(12, 49), 256, 0, stream>>>(z, w1T, 384, 1536, b1 + (size_t)d * 1536,
                                                   nullptr, nullptr, nullptr, hid, nullptr);
    k_gemm<3, 2><<<dim3(3, 98), 256, 0, stream>>>(hid, w2T, 1536, 384, b2 + (size_t)d * 384,
                                                  nullptr, h, nullptr, nullptr, h);
  }

  // transpose head_w (384,1000) -> hwT (1000,384) fp32 (hid buffer is free now)
  k_tcastf<<<dim3(32, 12), tb, 0, stream>>>(head_w, hwT, 384, 1000);

  k_ln<<<1568, 256, 0, stream>>>(h, z, lnf_s, lnf_b);
  k_pool<<<32, 384, 0, stream>>>(z, pooled);
  k_head<<<8000, 256, 0, stream>>>(pooled, hwT, head_b, out);
}